// Round 6
// baseline (125.215 us; speedup 1.0000x reference)
//
#include <hip/hip_runtime.h>

#define B 4096
#define S 200
#define EMB_DIM 128
#define HIDDEN 256
#define NUM_CLASSES 20
#define VOCAB 100000
#define RB 4               // batch rows per block, gathered as 2 pairs

// ---------------------------------------------------------------------------
// Single fused kernel: gather + mean-pool + MLP, straight from the fp32 table.
//
// R5 post-mortem: fused time (~30 us) is IDENTICAL for 105 MB bf16 and 56 MB
// int8 gathers -> the table-read path is not BW-saturated, so the convert
// pass's sole purpose (shrink gathered bytes) is void. The 51.2 MB of cold
// HBM first-touch is paid either way (poison flushes L3 every iteration);
// convert merely streamed it and added a 12.8 MB write + a launch. This
// version deletes convert (-10 us if the fused floor is byte-insensitive,
// which R2-R5 all indicate) and gathers 512 B fp32 rows directly:
//   d = t&31 (16B slot of the row), g = t>>5 (8 position groups),
//   2 row-pairs, 8 unguarded uint4 loads in flight (R4-proven shape),
//   32 positions/row/round (<=7 rounds; round count proven irrelevant, R2).
// No dequant VALU, no scale loads, exact fp32 arithmetic (absmax improves).
// Padding positions read emb row 0 (all zeros, L1-hot). If instead the
// gather path saturates (~3.5-5 TB/s), this kernel will show up in the
// top-5 counters for the first time and measure that path directly.
// ---------------------------------------------------------------------------
__global__ __launch_bounds__(256, 4) void fused_kernel(
    const int* __restrict__ x,              // [B, S]
    const int* __restrict__ lens,           // [B]
    const float* __restrict__ emb,          // [VOCAB, EMB_DIM] fp32
    const float* __restrict__ W1,           // [EMB_DIM, HIDDEN]
    const float* __restrict__ b1,           // [HIDDEN]
    const float* __restrict__ W2,           // [HIDDEN, NUM_CLASSES]
    const float* __restrict__ b2,           // [NUM_CLASSES]
    float* __restrict__ out)                // [B, NUM_CLASSES]
{
    __shared__ int   sidx[RB][256];              // 4 KB
    __shared__ float tmp[RB][8][EMB_DIM];        // 16 KB (all 4 rows at once)
    __shared__ float P[RB][EMB_DIM];             // 2 KB
    __shared__ float H[RB][HIDDEN];              // 4 KB
    __shared__ float part[RB][2][NUM_CLASSES];   // 640 B

    const int t  = threadIdx.x;
    const int b0 = blockIdx.x * RB;

    int Ls[RB];
    #pragma unroll
    for (int r = 0; r < RB; ++r) {
        Ls[r] = lens[b0 + r];
        int v = 0;
        if (t < Ls[r]) v = x[(long)(b0 + r) * S + t];   // L <= 199 < 256
        sidx[r][t] = v;                                  // zeros beyond L
    }
    __syncthreads();

    const int g   = t >> 5;    // position group 0..7
    const int d   = t & 31;    // 16B slot (4 dims) of the 512B fp32 row
    const int dof = d << 2;    // element offset of the slot

    float acc[RB][4];
    #pragma unroll
    for (int r = 0; r < RB; ++r)
        #pragma unroll
        for (int f = 0; f < 4; ++f) acc[r][f] = 0.f;

    // Two pair-phases, each with 8 unguarded loads in flight (R4 shape).
    // Chunk j covers positions j*8+g within a 32-position round.
    #pragma unroll
    for (int pair = 0; pair < 2; ++pair) {
        const int na   = (Ls[pair * 2]     + 31) >> 5;   // 1..7
        const int nb   = (Ls[pair * 2 + 1] + 31) >> 5;   // 1..7
        const int nMax = na > nb ? na : nb;              // block-uniform

        int cur[2][4], nxt[2][4];
        #pragma unroll
        for (int p = 0; p < 2; ++p)
            #pragma unroll
            for (int j = 0; j < 4; ++j)
                cur[p][j] = sidx[pair * 2 + p][(j << 3) + g];

        for (int it = 0; it < nMax; ++it) {
            float4 v[2][4];
            #pragma unroll
            for (int p = 0; p < 2; ++p)
                #pragma unroll
                for (int j = 0; j < 4; ++j)
                    v[p][j] = *(const float4*)(emb + ((long)(cur[p][j] << 7) + dof));

            // prefetch next round's indices before the vmcnt wait
            // (max index = 7*32 + 31 = 255, always in bounds)
            const int nb2 = (it + 1) << 5;
            #pragma unroll
            for (int p = 0; p < 2; ++p)
                #pragma unroll
                for (int j = 0; j < 4; ++j)
                    nxt[p][j] = sidx[pair * 2 + p][((nb2 + (j << 3) + g) & 255)];

            #pragma unroll
            for (int p = 0; p < 2; ++p)
                #pragma unroll
                for (int j = 0; j < 4; ++j) {
                    acc[pair * 2 + p][0] += v[p][j].x;
                    acc[pair * 2 + p][1] += v[p][j].y;
                    acc[pair * 2 + p][2] += v[p][j].z;
                    acc[pair * 2 + p][3] += v[p][j].w;
                }

            #pragma unroll
            for (int p = 0; p < 2; ++p)
                #pragma unroll
                for (int j = 0; j < 4; ++j) cur[p][j] = nxt[p][j];
        }
    }

    // Single-barrier-pair reduce: all 4 rows' partials fit tmp at once.
    // Write: thread (g,d) stores 4 dims for each row; 8-lane groups cover
    // all 32 banks contiguously (conflict-free b128 writes).
    #pragma unroll
    for (int r = 0; r < RB; ++r)
        *(float4*)&tmp[r][g][dof] = *(float4*)acc[r];
    __syncthreads();

    // Reduce: 2 rows per pass x 2 passes, no barrier between (tmp read-only).
    #pragma unroll
    for (int pass = 0; pass < 2; ++pass) {
        const int r   = pass * 2 + (t >> 7);
        const int dim = t & 127;
        float s = 0.f;
        #pragma unroll
        for (int gg = 0; gg < 8; ++gg) s += tmp[r][gg][dim];
        P[r][dim] = s / (float)Ls[r];
    }
    __syncthreads();

    // Layer 1: hidden unit t for all 4 rows; W1 element read once per block.
    {
        float hA[RB], hB[RB];
        #pragma unroll
        for (int r = 0; r < RB; ++r) { hA[r] = 0.f; hB[r] = 0.f; }
        for (int k = 0; k < EMB_DIM; k += 2) {
            const float wa = W1[(k)     * HIDDEN + t];
            const float wb = W1[(k + 1) * HIDDEN + t];
            #pragma unroll
            for (int r = 0; r < RB; ++r) {
                hA[r] = fmaf(P[r][k],     wa, hA[r]);
                hB[r] = fmaf(P[r][k + 1], wb, hB[r]);
            }
        }
        const float bb = b1[t];
        #pragma unroll
        for (int r = 0; r < RB; ++r)
            H[r][t] = fmaxf(hA[r] + hB[r] + bb, 0.f);
    }
    __syncthreads();

    // Layer 2: RB rows x 2 k-segments x 20 classes = 160 threads, 128-FMA.
    if (t < RB * 2 * NUM_CLASSES) {
        const int r  = t / (2 * NUM_CLASSES);
        const int u  = t - r * 2 * NUM_CLASSES;
        const int j  = u / NUM_CLASSES;
        const int c  = u - j * NUM_CLASSES;
        const int k0 = j * 128;
        float a0 = 0.f, a1 = 0.f;
        for (int k = k0; k < k0 + 128; k += 2) {
            a0 = fmaf(H[r][k],     W2[(k)     * NUM_CLASSES + c], a0);
            a1 = fmaf(H[r][k + 1], W2[(k + 1) * NUM_CLASSES + c], a1);
        }
        part[r][j][c] = a0 + a1;
    }
    __syncthreads();

    if (t < RB * NUM_CLASSES) {
        const int r = t / NUM_CLASSES;
        const int c = t - r * NUM_CLASSES;
        out[(long)(b0 + r) * NUM_CLASSES + c] =
            b2[c] + part[r][0][c] + part[r][1][c];
    }
}

extern "C" void kernel_launch(void* const* d_in, const int* in_sizes, int n_in,
                              void* d_out, int out_size, void* d_ws, size_t ws_size,
                              hipStream_t stream) {
    const int*   x    = (const int*)d_in[0];
    const int*   lens = (const int*)d_in[1];
    const float* emb  = (const float*)d_in[2];
    const float* W1   = (const float*)d_in[3];
    const float* b1   = (const float*)d_in[4];
    const float* W2   = (const float*)d_in[5];
    const float* b2   = (const float*)d_in[6];
    float*       out  = (float*)d_out;

    fused_kernel<<<B / RB, 256, 0, stream>>>(x, lens, emb, W1, b1, W2, b2, out);
}

// Round 7
// 120.548 us; speedup vs baseline: 1.0387x; 1.0387x over previous
//
#include <hip/hip_runtime.h>

#define B 4096
#define S 200
#define EMB_DIM 128
#define HIDDEN 256
#define NUM_CLASSES 20
#define VOCAB 100000

// ---------------------------------------------------------------------------
// Pass 1 (unchanged from R5, measured ~10.2 us): fp32 table -> int8 with
// per-row scale. 51.2 MB read + 13.2 MB written, streamed. Row 0 stays all
// zero (scale 0) so padding reads are exact.
// ---------------------------------------------------------------------------
__global__ __launch_bounds__(256) void convert_q8(
    const float* __restrict__ emb,          // [VOCAB*EMB_DIM]
    signed char* __restrict__ qt,           // [VOCAB*EMB_DIM] int8
    float* __restrict__ scl)                // [VOCAB] per-row scale
{
    const int  t    = threadIdx.x;
    const long base = (long)blockIdx.x * 1024 + t * 4;   // element index
    const float4 v  = *(const float4*)(emb + base);

    float m = fmaxf(fmaxf(fabsf(v.x), fabsf(v.y)),
                    fmaxf(fabsf(v.z), fabsf(v.w)));
    #pragma unroll
    for (int off = 1; off < 32; off <<= 1)               // 32-lane row group
        m = fmaxf(m, __shfl_xor(m, off, 64));

    const float inv = m > 0.f ? 127.f / m : 0.f;
    const int q0 = __float2int_rn(v.x * inv);
    const int q1 = __float2int_rn(v.y * inv);
    const int q2 = __float2int_rn(v.z * inv);
    const int q3 = __float2int_rn(v.w * inv);
    const unsigned pk = (q0 & 255) | ((q1 & 255) << 8)
                      | ((q2 & 255) << 16) | ((q3 & 255) << 24);
    *(unsigned*)(qt + base) = pk;

    if ((t & 31) == 0) scl[base >> 7] = m * (1.f / 127.f);
}

// ---------------------------------------------------------------------------
// Pass 2: fused gather + mean-pool + MLP -- WAVE-INDEPENDENT gather.
//
// R6 measurement: fused gather runs at 2.2 TB/s with VALUBusy 23%, MFMA 0,
// Occupancy 33.6% -> ~70% of time nothing issues = concurrency-starved
// latency regime, not a byte ceiling (R4 vs R5: 105 vs 56 MB, same time).
// This version maximizes independent waves: 2 samples/block, 2 waves per
// sample (8192 waves = 32/CU potential, 2048 blocks = exactly 8 blocks/CU,
// one generation). No barriers in the gather loop; each wave owns alternate
// 8-position chunks of its sample and runs a depth-2 load pipeline:
//   lane l: slot = l>>3 (position in chunk), sub = l&7 (16B of 128B row)
//   -> one uint4 load covers 8 positions; scale dword rides along.
// In-wave shfl_xor reduce (lanes slot 0..7 hold the 128-dim partial) kills
// the 16 KB tmp buffer -> LDS ~8 KB; __launch_bounds__(256,8) targets
// VGPR<=64 for full 32-wave/CU residency. Padding chunks read row 0
// (int8 0, scale 0) -- exact, branch-free.
// ---------------------------------------------------------------------------
__global__ __launch_bounds__(256, 8) void fused_kernel(
    const int* __restrict__ x,              // [B, S]
    const int* __restrict__ lens,           // [B]
    const signed char* __restrict__ qt,     // [VOCAB, EMB_DIM] int8
    const float* __restrict__ scl,          // [VOCAB]
    const float* __restrict__ W1,           // [EMB_DIM, HIDDEN]
    const float* __restrict__ b1,           // [HIDDEN]
    const float* __restrict__ W2,           // [HIDDEN, NUM_CLASSES]
    const float* __restrict__ b2,           // [NUM_CLASSES]
    float* __restrict__ out)                // [B, NUM_CLASSES]
{
    __shared__ int   sidx[2][256];               // 2 KB
    __shared__ float Pp[4][EMB_DIM];             // 2 KB per-wave partials
    __shared__ float P[2][EMB_DIM];              // 1 KB
    __shared__ float H[2][HIDDEN];               // 2 KB
    __shared__ float part[2][4][NUM_CLASSES];    // 640 B

    const int t  = threadIdx.x;
    const int b0 = blockIdx.x * 2;

    const int L0 = lens[b0];
    const int L1 = lens[b0 + 1];
    {
        int v0i = 0; if (t < L0) v0i = x[(long)b0 * S + t];
        sidx[0][t] = v0i;                        // zeros beyond L (row 0)
        int v1i = 0; if (t < L1) v1i = x[(long)(b0 + 1) * S + t];
        sidx[1][t] = v1i;
    }
    __syncthreads();

    const int l    = t & 63;
    const int wid  = t >> 6;        // wave 0..3
    const int smp  = wid >> 1;      // sample 0/1 (uniform per wave)
    const int w    = wid & 1;       // wave-within-sample 0/1
    const int slot = l >> 3;        // position slot 0..7 within a chunk
    const int sub  = l & 7;         // 16B piece of the 128B int8 row
    const int soff = sub << 4;      // byte offset within the row

    const int L   = smp ? L1 : L0;                                   // no reg-array idx
    const int nCh = __builtin_amdgcn_readfirstlane((L + 7) >> 3);    // 1..25, scalar

    float acc[16];
    #pragma unroll
    for (int f = 0; f < 16; ++f) acc[f] = 0.f;

    // Depth-2 pipeline over this wave's chunks (w, w+2, w+4, ...).
    // Prefetch bound: max sidx index = (24+2)*8+7 = 215 < 256.
    int  idx0 = sidx[smp][(w << 3) + slot];
    uint4 v0  = *(const uint4*)(qt + (((long)idx0 << 7) + soff));
    float s0  = scl[idx0];

    for (int c = w; c < nCh; c += 2) {
        const int   idxN = sidx[smp][((c + 2) << 3) + slot];
        const uint4 vN   = *(const uint4*)(qt + (((long)idxN << 7) + soff));
        const float sN   = scl[idxN];

        #pragma unroll
        for (int q = 0; q < 4; ++q) {
            const unsigned cc = q == 0 ? v0.x : q == 1 ? v0.y : q == 2 ? v0.z : v0.w;
            acc[q * 4 + 0] = fmaf(s0, (float)((int)(cc << 24) >> 24), acc[q * 4 + 0]);
            acc[q * 4 + 1] = fmaf(s0, (float)((int)(cc << 16) >> 24), acc[q * 4 + 1]);
            acc[q * 4 + 2] = fmaf(s0, (float)((int)(cc <<  8) >> 24), acc[q * 4 + 2]);
            acc[q * 4 + 3] = fmaf(s0, (float)((int)(cc      ) >> 24), acc[q * 4 + 3]);
        }
        v0 = vN; s0 = sN; idx0 = idxN;
    }

    // In-wave reduce across the 8 position slots (lane bits 3,4,5).
    #pragma unroll
    for (int f = 0; f < 16; ++f) {
        acc[f] += __shfl_xor(acc[f],  8, 64);
        acc[f] += __shfl_xor(acc[f], 16, 64);
        acc[f] += __shfl_xor(acc[f], 32, 64);
    }
    if (slot == 0) {                 // lanes 0..7: dims [sub*16, sub*16+16)
        #pragma unroll
        for (int f = 0; f < 16; ++f)
            Pp[wid][(sub << 4) + f] = acc[f];
    }
    __syncthreads();

    // Combine the 2 waves' partials per sample; divide by L.
    {
        const int   s2  = t >> 7;            // sample 0/1
        const int   dim = t & 127;
        const float Lf  = (float)(s2 ? L1 : L0);
        P[s2][dim] = (Pp[2 * s2][dim] + Pp[2 * s2 + 1][dim]) / Lf;
    }
    __syncthreads();

    // Layer 1: hidden unit t for both rows (R0-proven shape).
    {
        float h0a = 0.f, h0b = 0.f, h1a = 0.f, h1b = 0.f;
        for (int k = 0; k < EMB_DIM; k += 2) {
            const float wa = W1[(k)     * HIDDEN + t];
            const float wb = W1[(k + 1) * HIDDEN + t];
            h0a = fmaf(P[0][k],     wa, h0a);  h0b = fmaf(P[0][k + 1], wb, h0b);
            h1a = fmaf(P[1][k],     wa, h1a);  h1b = fmaf(P[1][k + 1], wb, h1b);
        }
        const float bb = b1[t];
        H[0][t] = fmaxf(h0a + h0b + bb, 0.f);
        H[1][t] = fmaxf(h1a + h1b + bb, 0.f);
    }
    __syncthreads();

    // Layer 2: 2 rows x 4 k-segments x 20 classes = 160 threads, 64-FMA chains.
    if (t < 2 * 4 * NUM_CLASSES) {
        const int r  = t / (4 * NUM_CLASSES);
        const int u  = t - r * 4 * NUM_CLASSES;
        const int j  = u / NUM_CLASSES;
        const int c  = u - j * NUM_CLASSES;
        const int k0 = j * 64;
        float a = 0.f;
        for (int k = k0; k < k0 + 64; ++k)
            a = fmaf(H[r][k], W2[k * NUM_CLASSES + c], a);
        part[r][j][c] = a;
    }
    __syncthreads();

    if (t < 2 * NUM_CLASSES) {
        const int r = t / NUM_CLASSES;
        const int c = t - r * NUM_CLASSES;
        out[(long)(b0 + r) * NUM_CLASSES + c] =
            b2[c] + part[r][0][c] + part[r][1][c]
                  + part[r][2][c] + part[r][3][c];
    }
}

extern "C" void kernel_launch(void* const* d_in, const int* in_sizes, int n_in,
                              void* d_out, int out_size, void* d_ws, size_t ws_size,
                              hipStream_t stream) {
    const int*   x    = (const int*)d_in[0];
    const int*   lens = (const int*)d_in[1];
    const float* emb  = (const float*)d_in[2];
    const float* W1   = (const float*)d_in[3];
    const float* b1   = (const float*)d_in[4];
    const float* W2   = (const float*)d_in[5];
    const float* b2   = (const float*)d_in[6];
    float*       out  = (float*)d_out;

    signed char* qt  = (signed char*)d_ws;                   // 12.8 MB int8 table
    float*       scl = (float*)((char*)d_ws + (16l << 20));  // 400 KB row scales

    convert_q8<<<(VOCAB * EMB_DIM) / (4 * 256), 256, 0, stream>>>(emb, qt, scl);
    fused_kernel<<<B / 2, 256, 0, stream>>>(x, lens, qt, scl, W1, b1, W2, b2, out);
}